// Round 7
// baseline (277.341 us; speedup 1.0000x reference)
//
#include <hip/hip_runtime.h>

// Guided filter, guide==input (ref unused). 96 images of 512x512 f32.
// Ring-free delayed-recompute structure (verified rounds 4/6), now LDS-FREE:
// the horizontal 24-float window per quantity is {left lane's 8, own 8,
// right lane's 8}, fetched with DPP wave_shr1/wave_shl1 (VALU pipe) instead
// of LDS row buffers. bound_ctrl=1 zero-fills lanes 0/63 = image-edge pad.
// No LDS, no barriers, no fences: each wave is an independent straight-line
// stream. 16 bands x 96 images = 1536 single-wave blocks = 6 waves/CU.
// Round-6 evidence: LDS pipe saturated (119us vs 91us LDS floor), VALU 41%.
// This moves the window traffic to the idle VALU pipe.

#define RR   8
#define DD   17
#define WW   512
#define HH   512
#define BHH  32
#define NT   64
#define CPT  8
#define FEPS 1e-8f

union F4 { float4 v; float f[4]; };

__device__ __forceinline__ float frcp(float a) { return __builtin_amdgcn_rcpf(a); }

// lane l <- lane l-1 (lane 0 gets 0): DPP WAVE_SHR1 = 0x138, bound_ctrl=1
__device__ __forceinline__ float dpp_shr1(float x) {
    int i = __builtin_bit_cast(int, x);
    int r = __builtin_amdgcn_update_dpp(0, i, 0x138, 0xF, 0xF, true);
    return __builtin_bit_cast(float, r);
}
// lane l <- lane l+1 (lane 63 gets 0): DPP WAVE_SHL1 = 0x130, bound_ctrl=1
__device__ __forceinline__ float dpp_shl1(float x) {
    int i = __builtin_bit_cast(int, x);
    int r = __builtin_amdgcn_update_dpp(0, i, 0x130, 0xF, 0xF, true);
    return __builtin_bit_cast(float, r);
}

// Build the 24-float window [c0-8 .. c0+15] from a per-thread 8-col quantity.
// All branches calling this are wave-uniform (full exec mask for DPP).
__device__ __forceinline__ void hwin(const float* v, float* w) {
#pragma unroll
    for (int k = 0; k < CPT; ++k) {
        w[k]       = dpp_shr1(v[k]);   // cols c0-8..c0-1 (left lane)
        w[8 + k]   = v[k];             // cols c0  ..c0+7 (own)
        w[16 + k]  = dpp_shl1(v[k]);   // cols c0+8..c0+15 (right lane)
    }
}

// Horizontal 17-tap box of vertical sums + A/b math for row j.
// Identical DAG for the current and delayed-recompute instances =>
// bitwise-equal outputs for the same row => exact cancellation in va/vb.
__device__ __forceinline__ void stage1(const float* v1, const float* v2,
                                       int j, const float* inv_nx,
                                       float* Af, float* Bf)
{
    float w1[24], w2[24];
    hwin(v1, w1);
    hwin(v2, w2);
    float S1[CPT], S2[CPT];
    float s1 = 0.f, s2 = 0.f;
#pragma unroll
    for (int q = 0; q < DD; ++q) { s1 += w1[q]; s2 += w2[q]; }
    S1[0] = s1; S2[0] = s2;
#pragma unroll
    for (int k = 1; k < CPT; ++k) {
        S1[k] = S1[k-1] - w1[k-1] + w1[k-1+DD];
        S2[k] = S2[k-1] - w2[k-1] + w2[k-1+DD];
    }
    const int   ny    = min(HH - 1, j + RR) - max(0, j - RR) + 1;
    const float invny = frcp((float)ny);
#pragma unroll
    for (int k = 0; k < CPT; ++k) {
        float invN = invny * inv_nx[k];
        float mean = S1[k] * invN;
        float ex2  = S2[k] * invN;
        float var  = ex2 - mean * mean;
        float A    = var * frcp(var + FEPS);   // cov_xy == var_x (guide==input)
        Af[k] = A;
        Bf[k] = mean - A * mean;
    }
}

__global__ __launch_bounds__(NT, 2) void gf_kernel(
    const float* __restrict__ x, float* __restrict__ out)
{
    const int l   = threadIdx.x;          // 0..63 ; lane == thread (1 wave)
    const int img = blockIdx.y;
    const int r0  = blockIdx.x * BHH;
    const float* px = x   + (size_t)img * (HH * WW);
    float*       po = out + (size_t)img * (HH * WW);
    const int c0 = l * CPT;

    float inv_nx[CPT];
#pragma unroll
    for (int k = 0; k < CPT; ++k) {
        int c  = c0 + k;
        int nx = min(WW - 1, c + RR) - max(0, c - RR) + 1;
        inv_nx[k] = frcp((float)nx);
    }

    float v1[CPT]  = {0,0,0,0,0,0,0,0}, v2[CPT]  = {0,0,0,0,0,0,0,0};
    float v1d[CPT] = {0,0,0,0,0,0,0,0}, v2d[CPT] = {0,0,0,0,0,0,0,0};
    float va[CPT]  = {0,0,0,0,0,0,0,0}, vb[CPT]  = {0,0,0,0,0,0,0,0};

    const int rstart  = max(0, r0 - 2 * RR);
    const int rstart2 = max(0, r0 - RR);
    const int i2max   = r0 + BHH - 1;
    const int i1max   = min(HH - 1, i2max + RR);
    const int rend    = i2max + 2 * RR;

    // one-step-ahead prefetch of the three vertical-sum operand rows
    F4 xr_c[2], xm_c[2], xdd_c[2];
#pragma unroll
    for (int h = 0; h < 2; ++h) {
        xr_c[h].v = make_float4(0,0,0,0);
        xm_c[h].v = make_float4(0,0,0,0);
        xdd_c[h].v = make_float4(0,0,0,0);
    }
    {   // prime xr (rstart <= 495 < HH, always in-bounds)
        const float* p = px + (size_t)rstart * WW + c0;
        xr_c[0].v = *(const float4*)(p);
        xr_c[1].v = *(const float4*)(p + 4);
    }

#pragma unroll 1
    for (int r = rstart; r <= rend; ++r) {
        const int  i1    = r - RR;        // A/b row entering the window
        const int  jd    = i1 - DD;       // A/b row leaving (recomputed)
        const int  i2    = r - 2 * RR;    // output row
        const bool addV  = (r < HH);
        const bool subV  = (r - DD   >= rstart);
        const bool subVd = (r - 2*DD >= rstart);
        const bool addA  = (i1 >= rstart2) && (i1 <= i1max);
        const bool subA  = (jd >= rstart2);
        const bool st2   = (i2 >= r0);

        // prefetch next step's rows (no fences/barriers: loads stay in
        // flight under this step's ~500-instr VALU stream)
        const int rn = r + 1;
        F4 xr_n[2] = {xr_c[0], xr_c[1]};
        F4 xm_n[2] = {xm_c[0], xm_c[1]};
        F4 xdd_n[2] = {xdd_c[0], xdd_c[1]};
        if (rn < HH && rn <= rend) {
            const float* p = px + (size_t)rn * WW + c0;
            xr_n[0].v = *(const float4*)(p); xr_n[1].v = *(const float4*)(p + 4);
        }
        if (rn - DD >= rstart && rn <= rend) {
            const float* p = px + (size_t)(rn - DD) * WW + c0;
            xm_n[0].v = *(const float4*)(p); xm_n[1].v = *(const float4*)(p + 4);
        }
        if (rn - 2*DD >= rstart && rn <= rend) {
            const float* p = px + (size_t)(rn - 2*DD) * WW + c0;
            xdd_n[0].v = *(const float4*)(p); xdd_n[1].v = *(const float4*)(p + 4);
        }
        F4 xi[2];
        if (st2) {
            const float* p = px + (size_t)i2 * WW + c0;
            xi[0].v = *(const float4*)(p); xi[1].v = *(const float4*)(p + 4);
        }

        // vertical running sums (add-then-sub; delayed pair runs the
        // identical sequence 17 steps later -> bitwise equal)
#pragma unroll
        for (int k = 0; k < CPT; ++k) {
            const float xa = xr_c[k >> 2].f[k & 3];
            const float xb = xm_c[k >> 2].f[k & 3];
            const float xc = xdd_c[k >> 2].f[k & 3];
            if (addV)  { v1[k]  += xa; v2[k]  += xa * xa; }
            if (subV)  { v1[k]  -= xb; v2[k]  -= xb * xb; }
            if (subV)  { v1d[k] += xb; v2d[k] += xb * xb; }
            if (subVd) { v1d[k] -= xc; v2d[k] -= xc * xc; }
        }

        // ---- stage 1 (current): A/b row i1 enters the vertical window
        if (addA) {
            float Af[CPT], Bf[CPT];
            stage1(v1, v2, i1, inv_nx, Af, Bf);
#pragma unroll
            for (int k = 0; k < CPT; ++k) { va[k] += Af[k]; vb[k] += Bf[k]; }
        }
        // ---- stage 1 (delayed recompute): row jd leaves the window
        if (subA) {
            float Af[CPT], Bf[CPT];
            stage1(v1d, v2d, jd, inv_nx, Af, Bf);
#pragma unroll
            for (int k = 0; k < CPT; ++k) { va[k] -= Af[k]; vb[k] -= Bf[k]; }
        }

        // ---- stage 2: horizontal box of va/vb -> output row i2
        if (st2) {
            float wa[24], wb[24];
            hwin(va, wa);
            hwin(vb, wb);
            float SA[CPT], SB[CPT];
            float sa = 0.f, sb = 0.f;
#pragma unroll
            for (int q = 0; q < DD; ++q) { sa += wa[q]; sb += wb[q]; }
            SA[0] = sa; SB[0] = sb;
#pragma unroll
            for (int k = 1; k < CPT; ++k) {
                SA[k] = SA[k-1] - wa[k-1] + wa[k-1+DD];
                SB[k] = SB[k-1] - wb[k-1] + wb[k-1+DD];
            }
            const int   ny2   = min(HH - 1, i2 + RR) - max(0, i2 - RR) + 1;
            const float invny = frcp((float)ny2);
            F4 o0, o1;
#pragma unroll
            for (int k = 0; k < CPT; ++k) {
                float invN = invny * inv_nx[k];
                float ov   = (SA[k] * invN) * xi[k >> 2].f[k & 3] + SB[k] * invN;
                if (k < 4) o0.f[k] = ov; else o1.f[k - 4] = ov;
            }
            float* p = po + (size_t)i2 * WW + c0;
            *(float4*)(p)     = o0.v;
            *(float4*)(p + 4) = o1.v;
        }

        xr_c[0] = xr_n[0];  xr_c[1] = xr_n[1];
        xm_c[0] = xm_n[0];  xm_c[1] = xm_n[1];
        xdd_c[0] = xdd_n[0]; xdd_c[1] = xdd_n[1];
    }
}

extern "C" void kernel_launch(void* const* d_in, const int* in_sizes, int n_in,
                              void* d_out, int out_size, void* d_ws, size_t ws_size,
                              hipStream_t stream) {
    const float* x  = (const float*)d_in[0];   // d_in[1] (ref) unused
    float* out      = (float*)d_out;
    const int nimg  = in_sizes[0] / (HH * WW); // 96
    dim3 grid(HH / BHH, nimg);                 // 16 bands x 96 = 1536 blocks
    gf_kernel<<<grid, NT, 0, stream>>>(x, out);
}